// Round 1
// baseline (174.864 us; speedup 1.0000x reference)
//
#include <hip/hip_runtime.h>
#include <hip/hip_bf16.h>
#include <math.h>

#define D_PET 128
#define NK    256
#define NB    2048
#define NBATCH 16
#define KT    16   // k-tile per s_kernel block

__device__ __forceinline__ float silu(float x) {
    return x / (1.0f + expf(-x));
}

__device__ __forceinline__ int lower_bound_dev(const int* a, int n, int v) {
    int lo = 0, hi = n;
    while (lo < hi) {
        int m = (lo + hi) >> 1;
        if (a[m] < v) lo = m + 1; else hi = m;
    }
    return lo;
}

// ---------------------------------------------------------------------------
// Kernel 1: filt[b,k,:] = MLP(kv[b,k,:])   grid = B*NK blocks, 128 threads
// ---------------------------------------------------------------------------
__global__ void mlp_kernel(const float* __restrict__ kvec,
                           const float* __restrict__ W1, const float* __restrict__ b1,
                           const float* __restrict__ W2, const float* __restrict__ b2,
                           const float* __restrict__ W3, const float* __restrict__ b3,
                           float* __restrict__ filt) {
    int bk = blockIdx.x;          // b*NK + k
    int d  = threadIdx.x;         // 0..127
    __shared__ float x[D_PET];

    float c0 = kvec[bk * 3 + 0];
    float c1 = kvec[bk * 3 + 1];
    float c2 = kvec[bk * 3 + 2];

    // layer 1: 3 -> 128, silu
    float a = b1[d] + c0 * W1[0 * D_PET + d] + c1 * W1[1 * D_PET + d] + c2 * W1[2 * D_PET + d];
    a = silu(a);
    x[d] = a;
    __syncthreads();

    // layer 2: 128 -> 128, silu
    float acc = b2[d];
#pragma unroll 8
    for (int e = 0; e < D_PET; e++) acc = fmaf(x[e], W2[e * D_PET + d], acc);
    acc = silu(acc);
    __syncthreads();
    x[d] = acc;
    __syncthreads();

    // layer 3: 128 -> 128
    float o = b3[d];
#pragma unroll 8
    for (int e = 0; e < D_PET; e++) o = fmaf(x[e], W3[e * D_PET + d], o);
    filt[bk * D_PET + d] = o;
}

// ---------------------------------------------------------------------------
// Kernel 2: cos/sin tables.  grid = NB blocks, NK threads
// ---------------------------------------------------------------------------
__global__ void phase_kernel(const float* __restrict__ kvec,
                             const float* __restrict__ pos,
                             const int* __restrict__ batch,
                             float* __restrict__ cos_t, float* __restrict__ sin_t) {
    int n = blockIdx.x;
    int k = threadIdx.x;
    int b = batch[n];
    float p0 = pos[n * 3 + 0], p1 = pos[n * 3 + 1], p2 = pos[n * 3 + 2];
    const float* kv = kvec + ((size_t)b * NK + k) * 3;
    float ph = p0 * kv[0] + p1 * kv[1] + p2 * kv[2];
    float s, c;
    sincosf(ph, &s, &c);
    cos_t[n * NK + k] = c;
    sin_t[n * NK + k] = s;
}

// ---------------------------------------------------------------------------
// Kernel 3: t[b,k,d] = (Σ_{n∈b} e^{-iφ_nk} h[n,d]) * filt[b,k,d]
// grid = B * (NK/KT) blocks, 256 threads.
// thread t: d = t&127, ks = t>>7; handles k = kbase + ks + 2*j, j=0..KT/2-1
// ---------------------------------------------------------------------------
__global__ void s_kernel(const float* __restrict__ h,
                         const float* __restrict__ cos_t,
                         const float* __restrict__ sin_t,
                         const int* __restrict__ batch,
                         const float* __restrict__ filt,
                         float* __restrict__ t_re, float* __restrict__ t_im) {
    const int tiles = NK / KT;
    int b  = blockIdx.x / tiles;
    int kt = blockIdx.x % tiles;
    int d  = threadIdx.x & (D_PET - 1);
    int ks = threadIdx.x >> 7;     // 0 or 1
    int kbase = kt * KT + ks;

    int lo = lower_bound_dev(batch, NB, b);
    int hi = lower_bound_dev(batch, NB, b + 1);

    float sre[KT / 2], sim[KT / 2];
#pragma unroll
    for (int j = 0; j < KT / 2; j++) { sre[j] = 0.f; sim[j] = 0.f; }

    for (int n = lo; n < hi; n++) {
        float hv = h[n * D_PET + d];
        const float* cr = cos_t + n * NK + kbase;
        const float* sr = sin_t + n * NK + kbase;
#pragma unroll
        for (int j = 0; j < KT / 2; j++) {
            float c = cr[2 * j];
            float s = sr[2 * j];
            sre[j] = fmaf(c, hv, sre[j]);
            sim[j] = fmaf(-s, hv, sim[j]);
        }
    }

#pragma unroll
    for (int j = 0; j < KT / 2; j++) {
        int k = kbase + 2 * j;
        size_t idx = ((size_t)b * NK + k) * D_PET + d;
        float f = filt[idx];
        t_re[idx] = sre[j] * f;
        t_im[idx] = sim[j] * f;
    }
}

// ---------------------------------------------------------------------------
// Kernel 4: out[n,d] = Σ_k e^{+iφ_nk} * t[batch[n],k,d]   (complex)
// grid = NB blocks, 128 threads
// ---------------------------------------------------------------------------
__global__ void out_kernel(const float* __restrict__ cos_t,
                           const float* __restrict__ sin_t,
                           const int* __restrict__ batch,
                           const float* __restrict__ t_re,
                           const float* __restrict__ t_im,
                           float* __restrict__ out, int interleaved) {
    int n = blockIdx.x;
    int d = threadIdx.x;
    int b = batch[n];

    __shared__ float cs[NK], sn[NK];
    for (int k = d; k < NK; k += D_PET) {
        cs[k] = cos_t[n * NK + k];
        sn[k] = sin_t[n * NK + k];
    }
    __syncthreads();

    const float* tr = t_re + (size_t)b * NK * D_PET + d;
    const float* ti = t_im + (size_t)b * NK * D_PET + d;

    float ore = 0.f, oim = 0.f;
#pragma unroll 4
    for (int k = 0; k < NK; k++) {
        float c  = cs[k];
        float s  = sn[k];
        float re = tr[(size_t)k * D_PET];
        float im = ti[(size_t)k * D_PET];
        ore = fmaf(c, re, ore);
        ore = fmaf(-s, im, ore);
        oim = fmaf(c, im, oim);
        oim = fmaf(s, re, oim);
    }

    if (interleaved) {
        ((float2*)out)[(size_t)n * D_PET + d] = make_float2(ore, oim);
    } else {
        out[(size_t)n * D_PET + d] = ore;
    }
}

// ---------------------------------------------------------------------------
extern "C" void kernel_launch(void* const* d_in, const int* in_sizes, int n_in,
                              void* d_out, int out_size, void* d_ws, size_t ws_size,
                              hipStream_t stream) {
    const float* kvec = (const float*)d_in[0];   // [16,256,3]
    const float* pos  = (const float*)d_in[1];   // [2048,3]
    const float* h    = (const float*)d_in[2];   // [2048,128]
    const float* W1   = (const float*)d_in[3];
    const float* b1   = (const float*)d_in[4];
    const float* W2   = (const float*)d_in[5];
    const float* b2   = (const float*)d_in[6];
    const float* W3   = (const float*)d_in[7];
    const float* b3   = (const float*)d_in[8];
    const int*   batch = (const int*)d_in[9];    // [2048]

    float* ws   = (float*)d_ws;
    float* filt  = ws;                                  // 16*256*128
    float* cos_t = filt  + (size_t)NBATCH * NK * D_PET; // 2048*256
    float* sin_t = cos_t + (size_t)NB * NK;
    float* t_re  = sin_t + (size_t)NB * NK;             // 16*256*128
    float* t_im  = t_re  + (size_t)NBATCH * NK * D_PET;

    int interleaved = (out_size == NB * D_PET * 2) ? 1 : 0;

    mlp_kernel<<<NBATCH * NK, D_PET, 0, stream>>>(kvec, W1, b1, W2, b2, W3, b3, filt);
    phase_kernel<<<NB, NK, 0, stream>>>(kvec, pos, batch, cos_t, sin_t);
    s_kernel<<<NBATCH * (NK / KT), 2 * D_PET, 0, stream>>>(h, cos_t, sin_t, batch, filt, t_re, t_im);
    out_kernel<<<NB, D_PET, 0, stream>>>(cos_t, sin_t, batch, t_re, t_im, (float*)d_out, interleaved);
}

// Round 2
// 165.667 us; speedup vs baseline: 1.0555x; 1.0555x over previous
//
#include <hip/hip_runtime.h>
#include <hip/hip_bf16.h>
#include <math.h>

#define D_PET 128
#define NK    256
#define NB    2048
#define NBATCH 16

__device__ __forceinline__ float silu(float x) {
    return x / (1.0f + expf(-x));
}

__device__ __forceinline__ int lower_bound_dev(const int* a, int n, int v) {
    int lo = 0, hi = n;
    while (lo < hi) {
        int m = (lo + hi) >> 1;
        if (a[m] < v) lo = m + 1; else hi = m;
    }
    return lo;
}

// ---------------------------------------------------------------------------
// Kernel 1: filt[b,k,:] = MLP(kv[b,k,:])
// 8 k-vectors per block, 256 threads: d = tid&127, jg = tid>>7 -> 4 j's each.
// W2/W3 column loads shared across 8 k-vectors -> L2 traffic /8.
// ---------------------------------------------------------------------------
#define MJ 8   // k-vectors per block
__global__ void mlp_kernel(const float* __restrict__ kvec,
                           const float* __restrict__ W1, const float* __restrict__ b1,
                           const float* __restrict__ W2, const float* __restrict__ b2,
                           const float* __restrict__ W3, const float* __restrict__ b3,
                           float* __restrict__ filt) {
    int bk0 = blockIdx.x * MJ;        // first (b*NK+k) of this block
    int d   = threadIdx.x & (D_PET - 1);
    int jg  = threadIdx.x >> 7;       // 0/1; this thread handles j = jg*4 + 0..3

    __shared__ float kv_s[MJ * 3];
    __shared__ float x_lds[D_PET * MJ];   // [e][j] layout, 4 KB

    if (threadIdx.x < MJ * 3) kv_s[threadIdx.x] = kvec[bk0 * 3 + threadIdx.x];
    __syncthreads();

    // ---- layer 1: 3 -> 128, silu ----
    float w10 = W1[0 * D_PET + d], w11 = W1[1 * D_PET + d], w12 = W1[2 * D_PET + d];
    float bb1 = b1[d];
    float4 x1;
    {
        float* xp = (float*)&x1;
#pragma unroll
        for (int i = 0; i < 4; i++) {
            int j = jg * 4 + i;
            float a = bb1;
            a = fmaf(kv_s[j * 3 + 0], w10, a);
            a = fmaf(kv_s[j * 3 + 1], w11, a);
            a = fmaf(kv_s[j * 3 + 2], w12, a);
            xp[i] = silu(a);
        }
    }
    *(float4*)&x_lds[(d << 3) + (jg << 2)] = x1;
    __syncthreads();

    // ---- layer 2: 128 -> 128, silu ----
    float acc0 = b2[d], acc1 = acc0, acc2 = acc0, acc3 = acc0;
#pragma unroll 4
    for (int e = 0; e < D_PET; e++) {
        float w = W2[e * D_PET + d];
        float4 xv = *(const float4*)&x_lds[(e << 3) + (jg << 2)];
        acc0 = fmaf(xv.x, w, acc0);
        acc1 = fmaf(xv.y, w, acc1);
        acc2 = fmaf(xv.z, w, acc2);
        acc3 = fmaf(xv.w, w, acc3);
    }
    float4 x2 = make_float4(silu(acc0), silu(acc1), silu(acc2), silu(acc3));
    __syncthreads();
    *(float4*)&x_lds[(d << 3) + (jg << 2)] = x2;
    __syncthreads();

    // ---- layer 3: 128 -> 128 ----
    float o0 = b3[d], o1 = o0, o2 = o0, o3 = o0;
#pragma unroll 4
    for (int e = 0; e < D_PET; e++) {
        float w = W3[e * D_PET + d];
        float4 xv = *(const float4*)&x_lds[(e << 3) + (jg << 2)];
        o0 = fmaf(xv.x, w, o0);
        o1 = fmaf(xv.y, w, o1);
        o2 = fmaf(xv.z, w, o2);
        o3 = fmaf(xv.w, w, o3);
    }
    float out4[4] = {o0, o1, o2, o3};
#pragma unroll
    for (int i = 0; i < 4; i++) {
        int j = jg * 4 + i;
        filt[(size_t)(bk0 + j) * D_PET + d] = out4[i];
    }
}

// ---------------------------------------------------------------------------
// Kernel 2: cos/sin tables [n][k].  grid = NB blocks, NK threads
// ---------------------------------------------------------------------------
__global__ void phase_kernel(const float* __restrict__ kvec,
                             const float* __restrict__ pos,
                             const int* __restrict__ batch,
                             float* __restrict__ cos_t, float* __restrict__ sin_t) {
    int n = blockIdx.x;
    int k = threadIdx.x;
    int b = batch[n];
    float p0 = pos[n * 3 + 0], p1 = pos[n * 3 + 1], p2 = pos[n * 3 + 2];
    const float* kv = kvec + ((size_t)b * NK + k) * 3;
    float ph = p0 * kv[0] + p1 * kv[1] + p2 * kv[2];
    float s, c;
    sincosf(ph, &s, &c);
    cos_t[n * NK + k] = c;
    sin_t[n * NK + k] = s;
}

// ---------------------------------------------------------------------------
// Kernel 3: t[b,k,d] = (sum_{n in b} e^{-i phi_nk} h[n,d]) * filt[b,k,d]
// grid = 16 * 32 = 512 blocks, 256 threads.
// thread: d = tid&127, kg = tid>>7; handles k = kt*8 + kg*4 + 0..3
// per atom: 1 coalesced h load + 2 wave-uniform float4 loads + 8 FMA.
// ---------------------------------------------------------------------------
#define SKT 8   // k per block
__global__ void s_kernel(const float* __restrict__ h,
                         const float* __restrict__ cos_t,
                         const float* __restrict__ sin_t,
                         const int* __restrict__ batch,
                         const float* __restrict__ filt,
                         float* __restrict__ t_re, float* __restrict__ t_im) {
    const int tiles = NK / SKT;                 // 32
    int b  = blockIdx.x / tiles;
    int kt = blockIdx.x % tiles;
    int d  = threadIdx.x & (D_PET - 1);
    int kg = threadIdx.x >> 7;                  // 0/1
    int k0 = kt * SKT + kg * 4;

    int lo = lower_bound_dev(batch, NB, b);
    int hi = lower_bound_dev(batch, NB, b + 1);

    float sre0 = 0.f, sre1 = 0.f, sre2 = 0.f, sre3 = 0.f;
    float sim0 = 0.f, sim1 = 0.f, sim2 = 0.f, sim3 = 0.f;

    int n = lo;
    for (; n + 1 < hi; n += 2) {
        float hv0 = h[(size_t)n * D_PET + d];
        float hv1 = h[(size_t)(n + 1) * D_PET + d];
        float4 c0 = *(const float4*)&cos_t[(size_t)n * NK + k0];
        float4 s0 = *(const float4*)&sin_t[(size_t)n * NK + k0];
        float4 c1 = *(const float4*)&cos_t[(size_t)(n + 1) * NK + k0];
        float4 s1 = *(const float4*)&sin_t[(size_t)(n + 1) * NK + k0];
        sre0 = fmaf(c0.x, hv0, sre0); sim0 = fmaf(-s0.x, hv0, sim0);
        sre1 = fmaf(c0.y, hv0, sre1); sim1 = fmaf(-s0.y, hv0, sim1);
        sre2 = fmaf(c0.z, hv0, sre2); sim2 = fmaf(-s0.z, hv0, sim2);
        sre3 = fmaf(c0.w, hv0, sre3); sim3 = fmaf(-s0.w, hv0, sim3);
        sre0 = fmaf(c1.x, hv1, sre0); sim0 = fmaf(-s1.x, hv1, sim0);
        sre1 = fmaf(c1.y, hv1, sre1); sim1 = fmaf(-s1.y, hv1, sim1);
        sre2 = fmaf(c1.z, hv1, sre2); sim2 = fmaf(-s1.z, hv1, sim2);
        sre3 = fmaf(c1.w, hv1, sre3); sim3 = fmaf(-s1.w, hv1, sim3);
    }
    if (n < hi) {
        float hv0 = h[(size_t)n * D_PET + d];
        float4 c0 = *(const float4*)&cos_t[(size_t)n * NK + k0];
        float4 s0 = *(const float4*)&sin_t[(size_t)n * NK + k0];
        sre0 = fmaf(c0.x, hv0, sre0); sim0 = fmaf(-s0.x, hv0, sim0);
        sre1 = fmaf(c0.y, hv0, sre1); sim1 = fmaf(-s0.y, hv0, sim1);
        sre2 = fmaf(c0.z, hv0, sre2); sim2 = fmaf(-s0.z, hv0, sim2);
        sre3 = fmaf(c0.w, hv0, sre3); sim3 = fmaf(-s0.w, hv0, sim3);
    }

    float sre[4] = {sre0, sre1, sre2, sre3};
    float sim[4] = {sim0, sim1, sim2, sim3};
#pragma unroll
    for (int i = 0; i < 4; i++) {
        size_t idx = ((size_t)b * NK + k0 + i) * D_PET + d;
        float f = filt[idx];
        t_re[idx] = sre[i] * f;
        t_im[idx] = sim[i] * f;
    }
}

// ---------------------------------------------------------------------------
// Kernel 4: out[n,d] = sum_k e^{+i phi_nk} * t[batch[n],k,d]
// Block = 8 atoms of one batch, 256 threads: d = tid&127, ag = tid>>7 -> 4 atoms.
// t tiles staged in LDS (shared across the 8 atoms) -> t L2 traffic /8.
// Chunk-stride loop keeps the grid static for any batch-size distribution.
// ---------------------------------------------------------------------------
#define OCH 8      // atoms per chunk
#define OKT 32     // k-tile
#define CHUNKS 64  // grid chunks per batch (strided)
#define CSP 9      // padded cs row
__global__ void out_kernel(const float* __restrict__ cos_t,
                           const float* __restrict__ sin_t,
                           const int* __restrict__ batch,
                           const float* __restrict__ t_re,
                           const float* __restrict__ t_im,
                           float* __restrict__ out, int interleaved) {
    int b  = blockIdx.x / CHUNKS;
    int c0 = blockIdx.x % CHUNKS;

    int lo = lower_bound_dev(batch, NB, b);
    int hi = lower_bound_dev(batch, NB, b + 1);
    int sz = hi - lo;

    int d  = threadIdx.x & (D_PET - 1);
    int ag = threadIdx.x >> 7;    // 0/1 -> atoms ag*4 .. ag*4+3

    __shared__ float2 cs[NK * CSP];            // [k][atom(padded)] 18 KB
    __shared__ float  tr[OKT * D_PET];         // 16 KB
    __shared__ float  ti[OKT * D_PET];         // 16 KB

    const float* trg = t_re + (size_t)b * NK * D_PET;
    const float* tig = t_im + (size_t)b * NK * D_PET;

    for (int ch = c0; ch * OCH < sz; ch += CHUNKS) {
        int nb = lo + ch * OCH;

        // stage cos/sin rows for the 8 atoms: cs[k][a]
        for (int idx = threadIdx.x; idx < NK * OCH; idx += 256) {
            int a = idx >> 8;            // 0..7
            int k = idx & (NK - 1);
            int n = nb + a;
            float c = 0.f, s = 0.f;
            if (n < hi) {
                c = cos_t[(size_t)n * NK + k];
                s = sin_t[(size_t)n * NK + k];
            }
            cs[k * CSP + a] = make_float2(c, s);
        }

        float ore[4] = {0.f, 0.f, 0.f, 0.f};
        float oim[4] = {0.f, 0.f, 0.f, 0.f};

        for (int kt = 0; kt < NK; kt += OKT) {
            __syncthreads();   // cs staged (first iter) / previous compute done
            for (int idx = threadIdx.x * 4; idx < OKT * D_PET; idx += 256 * 4) {
                *(float4*)&tr[idx] = *(const float4*)&trg[(size_t)kt * D_PET + idx];
                *(float4*)&ti[idx] = *(const float4*)&tig[(size_t)kt * D_PET + idx];
            }
            __syncthreads();
#pragma unroll 4
            for (int kk = 0; kk < OKT; kk++) {
                float tre = tr[kk * D_PET + d];
                float tim = ti[kk * D_PET + d];
                int k = kt + kk;
#pragma unroll
                for (int j = 0; j < 4; j++) {
                    float2 p = cs[k * CSP + ag * 4 + j];
                    ore[j] = fmaf(p.x, tre, ore[j]);
                    ore[j] = fmaf(-p.y, tim, ore[j]);
                    oim[j] = fmaf(p.x, tim, oim[j]);
                    oim[j] = fmaf(p.y, tre, oim[j]);
                }
            }
        }
        __syncthreads();   // protect cs/tr/ti before next chunk restages

#pragma unroll
        for (int j = 0; j < 4; j++) {
            int n = nb + ag * 4 + j;
            if (n < hi) {
                if (interleaved) {
                    ((float2*)out)[(size_t)n * D_PET + d] = make_float2(ore[j], oim[j]);
                } else {
                    out[(size_t)n * D_PET + d] = ore[j];
                }
            }
        }
    }
}

// ---------------------------------------------------------------------------
extern "C" void kernel_launch(void* const* d_in, const int* in_sizes, int n_in,
                              void* d_out, int out_size, void* d_ws, size_t ws_size,
                              hipStream_t stream) {
    const float* kvec = (const float*)d_in[0];   // [16,256,3]
    const float* pos  = (const float*)d_in[1];   // [2048,3]
    const float* h    = (const float*)d_in[2];   // [2048,128]
    const float* W1   = (const float*)d_in[3];
    const float* b1   = (const float*)d_in[4];
    const float* W2   = (const float*)d_in[5];
    const float* b2   = (const float*)d_in[6];
    const float* W3   = (const float*)d_in[7];
    const float* b3   = (const float*)d_in[8];
    const int*   batch = (const int*)d_in[9];    // [2048]

    float* ws    = (float*)d_ws;
    float* filt  = ws;                                  // 16*256*128
    float* cos_t = filt  + (size_t)NBATCH * NK * D_PET; // 2048*256
    float* sin_t = cos_t + (size_t)NB * NK;
    float* t_re  = sin_t + (size_t)NB * NK;             // 16*256*128
    float* t_im  = t_re  + (size_t)NBATCH * NK * D_PET;

    int interleaved = (out_size == NB * D_PET * 2) ? 1 : 0;

    mlp_kernel<<<NBATCH * NK / MJ, 256, 0, stream>>>(kvec, W1, b1, W2, b2, W3, b3, filt);
    phase_kernel<<<NB, NK, 0, stream>>>(kvec, pos, batch, cos_t, sin_t);
    s_kernel<<<NBATCH * (NK / SKT), 256, 0, stream>>>(h, cos_t, sin_t, batch, filt, t_re, t_im);
    out_kernel<<<NBATCH * CHUNKS, 256, 0, stream>>>(cos_t, sin_t, batch, t_re, t_im, (float*)d_out, interleaved);
}